// Round 4
// baseline (70.478 us; speedup 1.0000x reference)
//
#include <hip/hip_runtime.h>

#define BB 32
#define CC 384
#define TT 512
#define MAXF 6656      // T * 13
#define CG 8           // channels per block
#define NCHUNK 7       // ceil(6656 / 1024), last chunk is half

typedef float f32x4 __attribute__((ext_vector_type(4)));

__device__ __forceinline__ void nt_store4(float* p, float a, float b, float c, float d) {
    f32x4 v; v.x = a; v.y = b; v.z = c; v.w = d;
    __builtin_nontemporal_store(v, (f32x4*)p);
}

__device__ __forceinline__ void nt_zero4(float* p) {
    f32x4 v = (f32x4)0.0f;
    __builtin_nontemporal_store(v, (f32x4*)p);
}

__device__ __forceinline__ int rep_count(float d) {
    float fr = 44100.0f * d;
    float rf;
    if (fr - 1024.0f > 0.0f) rf = fmaxf((fr - 1024.0f) * (1.0f / 256.0f), 1.0f);
    else rf = (d == 0.0f) ? 0.0f : 1.0f;
    return (int)rf;
}

// Round-3 skeleton with ONE change under test: store order is now
// channel-outer / chunk-inner, so each block writes its 8 adjacent rows
// (one contiguous 213 KB span) as a linear ascending stream instead of
// 8 interleaved 4KB-step streams. stok is preloaded to registers.
__global__ __launch_bounds__(256) void lr_fused_co_kernel(
        const float* __restrict__ x,
        const float* __restrict__ notepitch,
        const float* __restrict__ duration,
        float* __restrict__ out,
        float* __restrict__ pitch_out,
        float* __restrict__ fl_out) {
    __shared__ float xs[CG * TT];                                      // 16 KB
    __shared__ float snp[TT];                                          // 2 KB
    __shared__ __attribute__((aligned(16))) unsigned short stok[MAXF]; // 13 KB
    __shared__ int wsum[4];

    const int b    = blockIdx.y;
    const int cg   = blockIdx.x;
    const int tid  = threadIdx.x;
    const int lane = tid & 63;
    const int wid  = tid >> 6;
    const bool do_pitch = (cg == 0);

    // ---- duration first (scan's waitcnt then leaves x loads in flight) ----
    const float2 dp = *(const float2*)(duration + b * TT + 2 * tid);

    // ---- issue x staging loads (latency overlapped with scan + zero phase) ----
    const float4* xsrc = (const float4*)(x + ((size_t)(b * CC + cg * CG)) * TT);
    const float4 xa0 = xsrc[tid];
    const float4 xa1 = xsrc[256 + tid];
    const float4 xa2 = xsrc[512 + tid];
    const float4 xa3 = xsrc[768 + tid];
    float2 np2 = make_float2(0.f, 0.f);
    if (do_pitch) np2 = *(const float2*)(notepitch + b * TT + 2 * tid);

    // ---- repeat counts for tokens 2*tid, 2*tid+1 ----
    const int r0 = rep_count(dp.x);
    const int r1 = rep_count(dp.y);
    const int s  = r0 + r1;

    // ---- shuffle scan of pair sums within wave, LDS combine across waves ----
    int v = s;
    #pragma unroll
    for (int off = 1; off < 64; off <<= 1) {
        const int t = __shfl_up(v, off, 64);
        if (lane >= off) v += t;
    }
    if (lane == 63) wsum[wid] = v;
    __syncthreads();

    int prefix = 0, total = 0;
    #pragma unroll
    for (int w = 0; w < 4; ++w) {
        const int t = wsum[w];
        total += t;
        if (w < wid) prefix += t;
    }
    const int incl = v + prefix;     // inclusive over pairs -> cum[2*tid+1]
    const int excl = incl - s;       // start frame of token 2*tid
    const int fl   = total;          // frame_lengths[b]

    if (do_pitch && tid == 0) fl_out[b] = (float)fl;

    float* const obase = out + ((size_t)(b * CC + cg * CG)) * MAXF;
    float* const pb    = pitch_out + (size_t)b * MAXF;

    // ---- phase 1: pure zero chunks, channel-outer (linear per row) ----
    #pragma unroll
    for (int c = 0; c < CG; ++c) {
        float* const ob = obase + (size_t)c * MAXF;
        #pragma unroll
        for (int ch = 0; ch < NCHUNK; ++ch) {
            const int base = ch * 1024;
            const int p0 = base + tid * 4;
            if (base >= fl && p0 < MAXF)
                nt_zero4(ob + p0);
        }
    }
    if (do_pitch) {
        #pragma unroll
        for (int ch = 0; ch < NCHUNK; ++ch) {
            const int base = ch * 1024;
            const int p0 = base + tid * 4;
            if (base >= fl && p0 < MAXF)
                nt_zero4(pb + p0);
        }
    }

    // ---- stage x rows / pitch into LDS (loads have arrived by now) ----
    {
        float4* xdst = (float4*)xs;
        xdst[tid] = xa0; xdst[256 + tid] = xa1;
        xdst[512 + tid] = xa2; xdst[768 + tid] = xa3;
    }
    if (do_pitch) *(float2*)(snp + 2 * tid) = np2;

    // ---- scatter inversion: token t owns frames [excl_t, excl_t + r_t) ----
    for (int f = excl; f < excl + r0; ++f)       stok[f] = (unsigned short)(2 * tid);
    for (int f = excl + r0; f < incl; ++f)       stok[f] = (unsigned short)(2 * tid + 1);
    __syncthreads();

    // ---- preload this thread's tok quads for all chunks (7 ds_read_b64) ----
    ushort4 tkv[NCHUNK];
    #pragma unroll
    for (int ch = 0; ch < NCHUNK; ++ch) {
        const int p0 = ch * 1024 + tid * 4;
        if (p0 < MAXF) tkv[ch] = *(const ushort4*)(stok + p0);
        else           tkv[ch] = make_ushort4(0, 0, 0, 0);
    }

    // ---- phase 2: valid / mixed chunks, channel-outer (linear per row) ----
    #pragma unroll
    for (int c = 0; c < CG; ++c) {
        const float* const xr = xs + c * TT;
        float* const ob = obase + (size_t)c * MAXF;
        #pragma unroll
        for (int ch = 0; ch < NCHUNK; ++ch) {
            const int base = ch * 1024;
            const int p0 = base + tid * 4;
            if (base >= fl || p0 >= MAXF) continue;

            const ushort4 tk = tkv[ch];
            if (base + 1024 <= fl) {
                // fully valid: unmasked gathers (tok < 512 guaranteed)
                nt_store4(ob + p0, xr[tk.x], xr[tk.y], xr[tk.z], xr[tk.w]);
            } else {
                // mixed: clamp garbage tokens (stok uninit beyond fl), mask tail
                const int u0 = min((int)tk.x, TT - 1), u1 = min((int)tk.y, TT - 1);
                const int u2 = min((int)tk.z, TT - 1), u3 = min((int)tk.w, TT - 1);
                const bool m0 = p0 < fl, m1 = p0 + 1 < fl;
                const bool m2 = p0 + 2 < fl, m3 = p0 + 3 < fl;
                nt_store4(ob + p0,
                          m0 ? xr[u0] : 0.f,
                          m1 ? xr[u1] : 0.f,
                          m2 ? xr[u2] : 0.f,
                          m3 ? xr[u3] : 0.f);
            }
        }
    }
    if (do_pitch) {
        #pragma unroll
        for (int ch = 0; ch < NCHUNK; ++ch) {
            const int base = ch * 1024;
            const int p0 = base + tid * 4;
            if (base >= fl || p0 >= MAXF) continue;

            const ushort4 tk = tkv[ch];
            if (base + 1024 <= fl) {
                nt_store4(pb + p0,
                          (float)(int)snp[tk.x], (float)(int)snp[tk.y],
                          (float)(int)snp[tk.z], (float)(int)snp[tk.w]);
            } else {
                const int u0 = min((int)tk.x, TT - 1), u1 = min((int)tk.y, TT - 1);
                const int u2 = min((int)tk.z, TT - 1), u3 = min((int)tk.w, TT - 1);
                const bool m0 = p0 < fl, m1 = p0 + 1 < fl;
                const bool m2 = p0 + 2 < fl, m3 = p0 + 3 < fl;
                nt_store4(pb + p0,
                          m0 ? (float)(int)snp[u0] : 0.f,
                          m1 ? (float)(int)snp[u1] : 0.f,
                          m2 ? (float)(int)snp[u2] : 0.f,
                          m3 ? (float)(int)snp[u3] : 0.f);
            }
        }
    }
}

extern "C" void kernel_launch(void* const* d_in, const int* in_sizes, int n_in,
                              void* d_out, int out_size, void* d_ws, size_t ws_size,
                              hipStream_t stream) {
    (void)in_sizes; (void)n_in; (void)out_size; (void)d_ws; (void)ws_size;

    const float* x         = (const float*)d_in[0];  // (B, C, T)
    const float* notepitch = (const float*)d_in[1];  // (B, T)
    const float* duration  = (const float*)d_in[2];  // (B, T)
    // d_in[3] = x_lengths — unused by the reference computation

    float* out       = (float*)d_out;                    // (B, C, MAXF)
    float* pitch_out = out + (size_t)BB * CC * MAXF;     // (B, MAXF)
    float* fl_out    = pitch_out + (size_t)BB * MAXF;    // (B,)

    dim3 g(CC / CG, BB);   // 48 x 32 = 1536 blocks
    lr_fused_co_kernel<<<g, 256, 0, stream>>>(x, notepitch, duration,
                                              out, pitch_out, fl_out);
}

// Round 5
// 70.262 us; speedup vs baseline: 1.0031x; 1.0031x over previous
//
#include <hip/hip_runtime.h>

#define BB 32
#define CC 384
#define TT 512
#define MAXF 6656      // T * 13
#define CG 8           // channels per tile
#define NCHUNK 7       // ceil(6656 / 1024), last chunk is half
#define NTILE 6        // cg tiles per block -> 48 rows per block
// grid = BB * (CC/CG/NTILE) = 32 * 8 = 256 blocks (1 per CU)

typedef float f32x4 __attribute__((ext_vector_type(4)));

__device__ __forceinline__ void nt_store4(float* p, float a, float b, float c, float d) {
    f32x4 v; v.x = a; v.y = b; v.z = c; v.w = d;
    __builtin_nontemporal_store(v, (f32x4*)p);
}

__device__ __forceinline__ void nt_zero4(float* p) {
    f32x4 v = (f32x4)0.0f;
    __builtin_nontemporal_store(v, (f32x4*)p);
}

__device__ __forceinline__ int rep_count(float d) {
    float fr = 44100.0f * d;
    float rf;
    if (fr - 1024.0f > 0.0f) rf = fmaxf((fr - 1024.0f) * (1.0f / 256.0f), 1.0f);
    else rf = (d == 0.0f) ? 0.0f : 1.0f;
    return (int)rf;
}

// Persistent-style: 256 blocks, each owns 48 adjacent output rows (6 tiles
// of 8 channels). ONE mechanism under test vs the 69.1us baseline: the
// number of concurrently-advancing DRAM write windows (1280 -> 256).
// Same bytes, same gathers, same store width, NT stores kept (proven neutral).
__global__ __launch_bounds__(256) void lr_persist_kernel(
        const float* __restrict__ x,
        const float* __restrict__ notepitch,
        const float* __restrict__ duration,
        float* __restrict__ out,
        float* __restrict__ pitch_out,
        float* __restrict__ fl_out) {
    __shared__ float xs[CG * TT];                                      // 16 KB
    __shared__ float snp[TT];                                          // 2 KB
    __shared__ __attribute__((aligned(16))) unsigned short stok[MAXF]; // 13 KB
    __shared__ int wsum[4];

    const int blk  = blockIdx.x;
    const int b    = blk >> 3;              // 8 blocks per batch
    const int cg0  = (blk & 7) * NTILE;     // first cg tile (0,6,12,...,42)
    const int tid  = threadIdx.x;
    const int lane = tid & 63;
    const int wid  = tid >> 6;
    const bool pw  = ((blk & 7) == 0);      // pitch-owning block for batch b

    // ---- duration first (scan's waitcnt leaves x loads in flight) ----
    const float2 dp = *(const float2*)(duration + b * TT + 2 * tid);

    // ---- prologue: issue tile-0 x loads ----
    const float4* xsrc0 = (const float4*)(x + ((size_t)(b * CC + cg0 * CG)) * TT);
    float4 xa0 = xsrc0[tid];
    float4 xa1 = xsrc0[256 + tid];
    float4 xa2 = xsrc0[512 + tid];
    float4 xa3 = xsrc0[768 + tid];
    float2 np2 = make_float2(0.f, 0.f);
    if (pw) np2 = *(const float2*)(notepitch + b * TT + 2 * tid);

    // ---- repeat counts + scan (identical math to baseline) ----
    const int r0 = rep_count(dp.x);
    const int r1 = rep_count(dp.y);
    const int s  = r0 + r1;

    int v = s;
    #pragma unroll
    for (int off = 1; off < 64; off <<= 1) {
        const int t = __shfl_up(v, off, 64);
        if (lane >= off) v += t;
    }
    if (lane == 63) wsum[wid] = v;
    __syncthreads();

    int prefix = 0, total = 0;
    #pragma unroll
    for (int w = 0; w < 4; ++w) {
        const int t = wsum[w];
        total += t;
        if (w < wid) prefix += t;
    }
    const int incl = v + prefix;     // inclusive over pairs -> cum[2*tid+1]
    const int excl = incl - s;       // start frame of token 2*tid
    const int fl   = total;          // frame_lengths[b]

    if (pw && tid == 0) fl_out[b] = (float)fl;

    // ---- zero phase: all 48 rows (one contiguous 1.2 MB span per block) ----
    float* const orow0 = out + ((size_t)(b * CC + cg0 * CG)) * MAXF;
    float* const pb    = pitch_out + (size_t)b * MAXF;
    for (int c = 0; c < CG * NTILE; ++c) {
        float* const ob = orow0 + (size_t)c * MAXF;
        #pragma unroll
        for (int ch = 0; ch < NCHUNK; ++ch) {
            const int base = ch * 1024;
            const int p0 = base + tid * 4;
            if (base >= fl && p0 < MAXF)
                nt_zero4(ob + p0);
        }
    }
    if (pw) {
        #pragma unroll
        for (int ch = 0; ch < NCHUNK; ++ch) {
            const int base = ch * 1024;
            const int p0 = base + tid * 4;
            if (base >= fl && p0 < MAXF)
                nt_zero4(pb + p0);
        }
    }

    // ---- scatter inversion + pitch staging ----
    for (int f = excl; f < excl + r0; ++f)       stok[f] = (unsigned short)(2 * tid);
    for (int f = excl + r0; f < incl; ++f)       stok[f] = (unsigned short)(2 * tid + 1);
    if (pw) *(float2*)(snp + 2 * tid) = np2;
    __syncthreads();

    // ---- preload tok quads once (reused across all 6 tiles) ----
    ushort4 tkv[NCHUNK];
    #pragma unroll
    for (int ch = 0; ch < NCHUNK; ++ch) {
        const int p0 = ch * 1024 + tid * 4;
        if (p0 < MAXF) tkv[ch] = *(const ushort4*)(stok + p0);
        else           tkv[ch] = make_ushort4(0, 0, 0, 0);
    }

    // ---- tile loop: stage 8 rows -> gather-store, next tile prefetched ----
    for (int t = 0; t < NTILE; ++t) {
        // stage current tile (regs hold it; compiler inserts the vmcnt wait)
        {
            float4* xdst = (float4*)xs;
            xdst[tid] = xa0; xdst[256 + tid] = xa1;
            xdst[512 + tid] = xa2; xdst[768 + tid] = xa3;
        }
        // prefetch next tile's rows into registers (in flight during gather)
        if (t + 1 < NTILE) {
            const float4* xn =
                (const float4*)(x + ((size_t)(b * CC + (cg0 + t + 1) * CG)) * TT);
            xa0 = xn[tid]; xa1 = xn[256 + tid];
            xa2 = xn[512 + tid]; xa3 = xn[768 + tid];
        }
        __syncthreads();   // xs ready for all waves

        float* const obase = out + ((size_t)(b * CC + (cg0 + t) * CG)) * MAXF;
        #pragma unroll
        for (int c = 0; c < CG; ++c) {
            const float* const xr = xs + c * TT;
            float* const ob = obase + (size_t)c * MAXF;
            #pragma unroll
            for (int ch = 0; ch < NCHUNK; ++ch) {
                const int base = ch * 1024;
                const int p0 = base + tid * 4;
                if (base >= fl || p0 >= MAXF) continue;

                const ushort4 tk = tkv[ch];
                if (base + 1024 <= fl) {
                    // fully valid: unmasked gathers (tok < 512 guaranteed)
                    nt_store4(ob + p0, xr[tk.x], xr[tk.y], xr[tk.z], xr[tk.w]);
                } else {
                    // mixed: clamp garbage tokens, mask tail
                    const int u0 = min((int)tk.x, TT - 1), u1 = min((int)tk.y, TT - 1);
                    const int u2 = min((int)tk.z, TT - 1), u3 = min((int)tk.w, TT - 1);
                    const bool m0 = p0 < fl, m1 = p0 + 1 < fl;
                    const bool m2 = p0 + 2 < fl, m3 = p0 + 3 < fl;
                    nt_store4(ob + p0,
                              m0 ? xr[u0] : 0.f,
                              m1 ? xr[u1] : 0.f,
                              m2 ? xr[u2] : 0.f,
                              m3 ? xr[u3] : 0.f);
                }
            }
        }
        if (pw && t == 0) {
            #pragma unroll
            for (int ch = 0; ch < NCHUNK; ++ch) {
                const int base = ch * 1024;
                const int p0 = base + tid * 4;
                if (base >= fl || p0 >= MAXF) continue;

                const ushort4 tk = tkv[ch];
                if (base + 1024 <= fl) {
                    nt_store4(pb + p0,
                              (float)(int)snp[tk.x], (float)(int)snp[tk.y],
                              (float)(int)snp[tk.z], (float)(int)snp[tk.w]);
                } else {
                    const int u0 = min((int)tk.x, TT - 1), u1 = min((int)tk.y, TT - 1);
                    const int u2 = min((int)tk.z, TT - 1), u3 = min((int)tk.w, TT - 1);
                    const bool m0 = p0 < fl, m1 = p0 + 1 < fl;
                    const bool m2 = p0 + 2 < fl, m3 = p0 + 3 < fl;
                    nt_store4(pb + p0,
                              m0 ? (float)(int)snp[u0] : 0.f,
                              m1 ? (float)(int)snp[u1] : 0.f,
                              m2 ? (float)(int)snp[u2] : 0.f,
                              m3 ? (float)(int)snp[u3] : 0.f);
                }
            }
        }
        if (t + 1 < NTILE) __syncthreads();  // all waves done reading xs
    }
}

extern "C" void kernel_launch(void* const* d_in, const int* in_sizes, int n_in,
                              void* d_out, int out_size, void* d_ws, size_t ws_size,
                              hipStream_t stream) {
    (void)in_sizes; (void)n_in; (void)out_size; (void)d_ws; (void)ws_size;

    const float* x         = (const float*)d_in[0];  // (B, C, T)
    const float* notepitch = (const float*)d_in[1];  // (B, T)
    const float* duration  = (const float*)d_in[2];  // (B, T)
    // d_in[3] = x_lengths — unused by the reference computation

    float* out       = (float*)d_out;                    // (B, C, MAXF)
    float* pitch_out = out + (size_t)BB * CC * MAXF;     // (B, MAXF)
    float* fl_out    = pitch_out + (size_t)BB * MAXF;    // (B,)

    lr_persist_kernel<<<256, 256, 0, stream>>>(x, notepitch, duration,
                                               out, pitch_out, fl_out);
}